// Round 5
// baseline (568.357 us; speedup 1.0000x reference)
//
#include <hip/hip_runtime.h>

#define N_NODE 50000
#define N_EDGE 625000
#define DIM 128
#define NUM_REL 8
#define EPS 1e-6f
#define NPC 32                                  // nodes per chunk (fused kernel)
#define SCAN_TILES ((N_NODE + 255) / 256)       // 196

// ===========================================================================
// CSR-build pipeline
// ===========================================================================

// K1: histogram of destination nodes (4 edges/thread)
__global__ __launch_bounds__(256) void rgc_hist(
    const int4* __restrict__ node_out4, unsigned* __restrict__ hist)
{
    int i = blockIdx.x * 256 + threadIdx.x;
    if (i < N_EDGE / 4) {
        int4 v = node_out4[i];
        atomicAdd(&hist[v.x], 1u);
        atomicAdd(&hist[v.y], 1u);
        atomicAdd(&hist[v.z], 1u);
        atomicAdd(&hist[v.w], 1u);
    }
}

// K2a: per-tile (256-element) sums of hist
__global__ __launch_bounds__(256) void rgc_scan1(
    const unsigned* __restrict__ hist, unsigned* __restrict__ partial)
{
    int idx = blockIdx.x * 256 + threadIdx.x;
    unsigned v = (idx < N_NODE) ? hist[idx] : 0u;
    #pragma unroll
    for (int o = 32; o > 0; o >>= 1) v += __shfl_down(v, o, 64);
    __shared__ unsigned ws[4];
    if ((threadIdx.x & 63) == 0) ws[threadIdx.x >> 6] = v;
    __syncthreads();
    if (threadIdx.x == 0) partial[blockIdx.x] = ws[0] + ws[1] + ws[2] + ws[3];
}

// K2b: per-tile exclusive scan; tile base computed in-block from partials
__global__ __launch_bounds__(256) void rgc_scan3(
    const unsigned* __restrict__ hist, const unsigned* __restrict__ partial,
    unsigned* __restrict__ offsets, unsigned* __restrict__ cursor)
{
    __shared__ unsigned lds[256];
    __shared__ unsigned wred[4];
    __shared__ unsigned base_sh;
    const int t   = threadIdx.x;
    const int blk = blockIdx.x;

    unsigned pv = (t < blk) ? partial[t] : 0u;
    #pragma unroll
    for (int o = 32; o > 0; o >>= 1) pv += __shfl_down(pv, o, 64);
    if ((t & 63) == 0) wred[t >> 6] = pv;
    __syncthreads();
    if (t == 0) base_sh = wred[0] + wred[1] + wred[2] + wred[3];

    int idx = blk * 256 + t;
    unsigned v = (idx < N_NODE) ? hist[idx] : 0u;
    lds[t] = v;
    for (int off = 1; off < 256; off <<= 1) {
        __syncthreads();
        unsigned u = (t >= off) ? lds[t - off] : 0u;
        __syncthreads();
        lds[t] += u;
    }
    __syncthreads();
    unsigned pos = base_sh + lds[t] - v;
    if (idx < N_NODE) { offsets[idx] = pos; cursor[idx] = pos; }
    if (idx == 0) offsets[N_NODE] = N_EDGE;
}

// K3: scatter edges into CSR order (4 edges/thread).
// perm[pos] = (w, pack) where pack = dstl(5)<<19 | rel(3)<<16 | src(16)
__global__ __launch_bounds__(256) void rgc_permute(
    const int4*   __restrict__ node_in4,
    const int4*   __restrict__ node_out4,
    const int4*   __restrict__ relation4,
    const float4* __restrict__ ew4,
    unsigned*     __restrict__ cursor,
    float2*       __restrict__ perm)
{
    int i = blockIdx.x * 256 + threadIdx.x;
    if (i >= N_EDGE / 4) return;
    int4   ni = node_in4[i];
    int4   no = node_out4[i];
    int4   rl = relation4[i];
    float4 w  = ew4[i];

    unsigned p0 = atomicAdd(&cursor[no.x], 1u);
    unsigned p1 = atomicAdd(&cursor[no.y], 1u);
    unsigned p2 = atomicAdd(&cursor[no.z], 1u);
    unsigned p3 = atomicAdd(&cursor[no.w], 1u);

    perm[p0] = make_float2(w.x, __uint_as_float(
        (unsigned)ni.x | ((unsigned)rl.x << 16) | (((unsigned)no.x & 31u) << 19)));
    perm[p1] = make_float2(w.y, __uint_as_float(
        (unsigned)ni.y | ((unsigned)rl.y << 16) | (((unsigned)no.y & 31u) << 19)));
    perm[p2] = make_float2(w.z, __uint_as_float(
        (unsigned)ni.z | ((unsigned)rl.z << 16) | (((unsigned)no.z & 31u) << 19)));
    perm[p3] = make_float2(w.w, __uint_as_float(
        (unsigned)ni.w | ((unsigned)rl.w << 16) | (((unsigned)no.w & 31u) << 19)));
}

// ===========================================================================
// K4: fused edge-parallel gather-sum (LDS f32 atomics) + matmul + epilogue
//   256 threads = 4 waves; lane j2 = tid&63 owns dims {2*j2, 2*j2+1}
//   aggs split-plane: aggs[c][l][j2] = dim 2*j2+c of node l  (ds_add bank-free)
// ===========================================================================
__global__ __launch_bounds__(256) void rgc_fused(
    const float*    __restrict__ x,        // [N_NODE, DIM]
    const float*    __restrict__ W,        // [DIM, DIM] (k, j)
    const float*    __restrict__ b,        // [DIM]
    const float*    __restrict__ rel_emb,  // [NUM_REL, DIM]
    const unsigned* __restrict__ offsets,  // [N_NODE+1]
    const float2*   __restrict__ perm,     // [N_EDGE]
    float*          __restrict__ out)      // [N_NODE, DIM]
{
    __shared__ float rel_lds[NUM_REL * DIM];   // 4 KB
    __shared__ float aggs[2][NPC][64];         // 16 KB
    __shared__ float cnts[NPC][NUM_REL];       // 1 KB

    const int tid  = threadIdx.x;
    const int j2   = tid & 63;
    const int slot = tid >> 6;
    const unsigned jo = (unsigned)(j2 * 8);

    for (int i = tid; i < NUM_REL * DIM; i += 256) rel_lds[i] = rel_emb[i];
    {   // zero aggs (4096 floats) and cnts (256 floats)
        float4* az = (float4*)aggs;
        for (int i = tid; i < 2 * NPC * 64 / 4; i += 256) az[i] = make_float4(0,0,0,0);
        cnts[tid >> 3][tid & 7] = 0.f;
    }
    __syncthreads();

    const int base = blockIdx.x * NPC;
    int hi = base + NPC; if (hi > N_NODE) hi = N_NODE;
    const int es = __builtin_amdgcn_readfirstlane((int)offsets[base]);
    const int ee = __builtin_amdgcn_readfirstlane((int)offsets[hi]);
    const char* xb = (const char*)x;
    const bool lane0 = (j2 == 0);

    // ---- phase 1: edge-parallel, interleaved quads per wave ----
    #define EDGE(idx)                                                          \
    {                                                                          \
        float2 p = perm[idx];                                                  \
        unsigned kk = __float_as_uint(p.y);                                    \
        const float2 v = *(const float2*)(xb + (((kk & 0xFFFFu) << 9) + jo));  \
        unsigned dl = kk >> 19;                                                \
        atomicAdd(&aggs[0][dl][j2], p.x * v.x);                                \
        atomicAdd(&aggs[1][dl][j2], p.x * v.y);                                \
        if (lane0) atomicAdd(&cnts[dl][(kk >> 16) & 7u], p.x);                 \
    }

    for (int i = es + slot * 4; i + 4 <= ee; i += 16) {
        EDGE(i + 0);
        EDGE(i + 1);
        EDGE(i + 2);
        EDGE(i + 3);
    }
    if (slot == 0) {
        for (int i = es + ((ee - es) & ~3); i < ee; ++i) EDGE(i);
    }
    #undef EDGE
    __syncthreads();

    // ---- phase 2: [8 nodes x 128] @ [128 x 128] per wave ----
    const int g = slot;
    float2 mm[8];
    #pragma unroll
    for (int m = 0; m < 8; ++m) mm[m] = make_float2(0.f, 0.f);

    for (int k2 = 0; k2 < 64; k2 += 4) {       // covers dims 2*k2 .. 2*k2+7
        float2 wv[8];
        #pragma unroll
        for (int c = 0; c < 8; ++c)
            wv[c] = *(const float2*)&W[(2 * k2 + c) * DIM + j2 * 2];
        #pragma unroll
        for (int m = 0; m < 8; ++m) {
            const float4 a0 = *(const float4*)&aggs[0][g * 8 + m][k2];
            const float4 a1 = *(const float4*)&aggs[1][g * 8 + m][k2];
            mm[m].x += a0.x * wv[0].x + a1.x * wv[1].x + a0.y * wv[2].x + a1.y * wv[3].x
                     + a0.z * wv[4].x + a1.z * wv[5].x + a0.w * wv[6].x + a1.w * wv[7].x;
            mm[m].y += a0.x * wv[0].y + a1.x * wv[1].y + a0.y * wv[2].y + a1.y * wv[3].y
                     + a0.z * wv[4].y + a1.z * wv[5].y + a0.w * wv[6].y + a1.w * wv[7].y;
        }
    }

    // ---- epilogue ----
    const float2 bv = *(const float2*)&b[j2 * 2];
    float2 rv[NUM_REL];
    #pragma unroll
    for (int r = 0; r < NUM_REL; ++r)
        rv[r] = *(const float2*)&rel_lds[r * DIM + j2 * 2];

    #pragma unroll
    for (int m = 0; m < 8; ++m) {
        const int l = g * 8 + m;
        const int n = base + l;
        if (n < N_NODE) {
            float dg = 0.f, rbx = 0.f, rby = 0.f;
            #pragma unroll
            for (int r = 0; r < NUM_REL; ++r) {
                const float c = cnts[l][r];
                dg  += c;
                rbx += c * rv[r].x;
                rby += c * rv[r].y;
            }
            const float inv = 1.0f / (dg + EPS);
            float yx = (mm[m].x + dg * bv.x + rbx) * inv;
            float yy = (mm[m].y + dg * bv.y + rby) * inv;
            *(float2*)&out[(size_t)n * DIM + j2 * 2] =
                make_float2(fmaxf(yx, 0.f), fmaxf(yy, 0.f));
        }
    }
}

// ===========================================================================
// Fallback path (old atomic scatter) in case ws_size is too small
// ===========================================================================
__global__ __launch_bounds__(256) void rgc_scatter(
    const float* __restrict__ x,
    const int*   __restrict__ node_in,
    const int*   __restrict__ node_out,
    const int*   __restrict__ relation,
    const float* __restrict__ ew,
    float*       __restrict__ agg,
    float*       __restrict__ cnt)
{
    int gid  = blockIdx.x * 256 + threadIdx.x;
    int e    = gid >> 5;
    int lane = gid & 31;
    if (e >= N_EDGE) return;
    int   src = node_in[e];
    int   dst = node_out[e];
    float w   = ew[e];
    const float4* x4 = reinterpret_cast<const float4*>(x + (size_t)src * DIM);
    float4 v = x4[lane];
    float* o = agg + (size_t)dst * DIM + lane * 4;
    atomicAdd(o + 0, v.x * w);
    atomicAdd(o + 1, v.y * w);
    atomicAdd(o + 2, v.z * w);
    atomicAdd(o + 3, v.w * w);
    if (lane == 0) atomicAdd(&cnt[(size_t)dst * NUM_REL + relation[e]], w);
}

__global__ __launch_bounds__(256) void rgc_finalize(
    const float* __restrict__ W,
    const float* __restrict__ b,
    const float* __restrict__ rel_emb,
    const float* __restrict__ cnt,
    float*       __restrict__ out,
    int nodes_per_block)
{
    __shared__ float Ws[DIM * DIM];
    __shared__ float bs[DIM];
    __shared__ float rs[NUM_REL * DIM];
    __shared__ float aggs2[2][DIM];
    for (int i = threadIdx.x; i < DIM * DIM; i += 256) Ws[i] = W[i];
    for (int i = threadIdx.x; i < DIM; i += 256)       bs[i] = b[i];
    for (int i = threadIdx.x; i < NUM_REL * DIM; i += 256) rs[i] = rel_emb[i];
    const int half = threadIdx.x >> 7;
    const int j    = threadIdx.x & 127;
    const int base = blockIdx.x * nodes_per_block;
    for (int nn = 0; nn < nodes_per_block; nn += 2) {
        const int n = base + nn + half;
        __syncthreads();
        if (n < N_NODE) aggs2[half][j] = out[(size_t)n * DIM + j];
        __syncthreads();
        if (n < N_NODE) {
            float acc = 0.f;
            #pragma unroll 16
            for (int k = 0; k < DIM; ++k)
                acc += aggs2[half][k] * Ws[k * DIM + j];
            float deg = 0.f, rbv = 0.f;
            #pragma unroll
            for (int r = 0; r < NUM_REL; ++r) {
                float c = cnt[(size_t)n * NUM_REL + r];
                deg += c;
                rbv += c * rs[r * DIM + j];
            }
            float y = (acc + deg * bs[j] + rbv) / (deg + EPS);
            out[(size_t)n * DIM + j] = fmaxf(y, 0.f);
        }
    }
}

// ===========================================================================
extern "C" void kernel_launch(void* const* d_in, const int* in_sizes, int n_in,
                              void* d_out, int out_size, void* d_ws, size_t ws_size,
                              hipStream_t stream) {
    const float* x        = (const float*)d_in[0];
    const int*   node_in  = (const int*)  d_in[1];
    const int*   node_out = (const int*)  d_in[2];
    const int*   relation = (const int*)  d_in[3];
    const float* ew       = (const float*)d_in[4];
    const float* W        = (const float*)d_in[5];
    const float* b        = (const float*)d_in[6];
    const float* rel_emb  = (const float*)d_in[7];
    float* out = (float*)d_out;

    // ws layout
    const size_t OFF_HIST   = 0;                       // u32[N_NODE]      200000 B
    const size_t OFF_CURSOR = 200000;                  // u32[N_NODE]      200000 B
    const size_t OFF_OFFS   = 400000;                  // u32[N_NODE+1]    200004 B
    const size_t OFF_PART   = 600064;                  // u32[SCAN_TILES]  784 B
    const size_t OFF_PERM   = 601088;                  // float2[N_EDGE]   5 MB
    const size_t WS_NEEDED  = OFF_PERM + (size_t)N_EDGE * sizeof(float2);

    if (ws_size < WS_NEEDED) {
        // fallback: atomic path (needs 1.6 MB)
        float* cnt = (float*)d_ws;
        hipMemsetAsync(d_out, 0, (size_t)N_NODE * DIM * sizeof(float), stream);
        hipMemsetAsync(cnt,   0, (size_t)N_NODE * NUM_REL * sizeof(float), stream);
        dim3 g1((N_EDGE * 32 + 255) / 256);
        rgc_scatter<<<g1, 256, 0, stream>>>(x, node_in, node_out, relation, ew, out, cnt);
        const int NPB = 16;
        dim3 g2((N_NODE + NPB - 1) / NPB);
        rgc_finalize<<<g2, 256, 0, stream>>>(W, b, rel_emb, cnt, out, NPB);
        return;
    }

    unsigned* hist    = (unsigned*)((char*)d_ws + OFF_HIST);
    unsigned* cursor  = (unsigned*)((char*)d_ws + OFF_CURSOR);
    unsigned* offsets = (unsigned*)((char*)d_ws + OFF_OFFS);
    unsigned* partial = (unsigned*)((char*)d_ws + OFF_PART);
    float2*   perm    = (float2*)  ((char*)d_ws + OFF_PERM);

    hipMemsetAsync(hist, 0, (size_t)N_NODE * sizeof(unsigned), stream);

    dim3 g4((N_EDGE / 4 + 255) / 256);   // 611
    rgc_hist<<<g4, 256, 0, stream>>>((const int4*)node_out, hist);
    rgc_scan1<<<SCAN_TILES, 256, 0, stream>>>(hist, partial);
    rgc_scan3<<<SCAN_TILES, 256, 0, stream>>>(hist, partial, offsets, cursor);
    rgc_permute<<<g4, 256, 0, stream>>>((const int4*)node_in, (const int4*)node_out,
                                        (const int4*)relation, (const float4*)ew,
                                        cursor, perm);

    dim3 gf((N_NODE + NPC - 1) / NPC);   // 1563
    rgc_fused<<<gf, 256, 0, stream>>>(x, W, b, rel_emb, offsets, perm, out);
}

// Round 6
// 154.552 us; speedup vs baseline: 3.6775x; 3.6775x over previous
//
#include <hip/hip_runtime.h>

#define N_NODE 50000
#define N_EDGE 625000
#define DIM 128
#define NUM_REL 8
#define EPS 1e-6f
#define NPC 32                                  // nodes per chunk (fused kernel)
#define SCAN_TILES ((N_NODE + 255) / 256)       // 196

// ===========================================================================
// CSR-build pipeline (int4 variants — kept from round 5, they were a win)
// ===========================================================================

// K1: histogram of destination nodes (4 edges/thread)
__global__ __launch_bounds__(256) void rgc_hist(
    const int4* __restrict__ node_out4, unsigned* __restrict__ hist)
{
    int i = blockIdx.x * 256 + threadIdx.x;
    if (i < N_EDGE / 4) {
        int4 v = node_out4[i];
        atomicAdd(&hist[v.x], 1u);
        atomicAdd(&hist[v.y], 1u);
        atomicAdd(&hist[v.z], 1u);
        atomicAdd(&hist[v.w], 1u);
    }
}

// K2a: per-tile (256-element) sums of hist
__global__ __launch_bounds__(256) void rgc_scan1(
    const unsigned* __restrict__ hist, unsigned* __restrict__ partial)
{
    int idx = blockIdx.x * 256 + threadIdx.x;
    unsigned v = (idx < N_NODE) ? hist[idx] : 0u;
    #pragma unroll
    for (int o = 32; o > 0; o >>= 1) v += __shfl_down(v, o, 64);
    __shared__ unsigned ws[4];
    if ((threadIdx.x & 63) == 0) ws[threadIdx.x >> 6] = v;
    __syncthreads();
    if (threadIdx.x == 0) partial[blockIdx.x] = ws[0] + ws[1] + ws[2] + ws[3];
}

// K2b: per-tile exclusive scan; tile base computed in-block from partials
__global__ __launch_bounds__(256) void rgc_scan3(
    const unsigned* __restrict__ hist, const unsigned* __restrict__ partial,
    unsigned* __restrict__ offsets, unsigned* __restrict__ cursor)
{
    __shared__ unsigned lds[256];
    __shared__ unsigned wred[4];
    __shared__ unsigned base_sh;
    const int t   = threadIdx.x;
    const int blk = blockIdx.x;

    unsigned pv = (t < blk) ? partial[t] : 0u;
    #pragma unroll
    for (int o = 32; o > 0; o >>= 1) pv += __shfl_down(pv, o, 64);
    if ((t & 63) == 0) wred[t >> 6] = pv;
    __syncthreads();
    if (t == 0) base_sh = wred[0] + wred[1] + wred[2] + wred[3];

    int idx = blk * 256 + t;
    unsigned v = (idx < N_NODE) ? hist[idx] : 0u;
    lds[t] = v;
    for (int off = 1; off < 256; off <<= 1) {
        __syncthreads();
        unsigned u = (t >= off) ? lds[t - off] : 0u;
        __syncthreads();
        lds[t] += u;
    }
    __syncthreads();
    unsigned pos = base_sh + lds[t] - v;
    if (idx < N_NODE) { offsets[idx] = pos; cursor[idx] = pos; }
    if (idx == 0) offsets[N_NODE] = N_EDGE;
}

// K3: scatter edges into CSR order (4 edges/thread).
// perm[pos] = (w, pack) where pack = dstl(5)<<19 | rel(3)<<16 | src(16)
__global__ __launch_bounds__(256) void rgc_permute(
    const int4*   __restrict__ node_in4,
    const int4*   __restrict__ node_out4,
    const int4*   __restrict__ relation4,
    const float4* __restrict__ ew4,
    unsigned*     __restrict__ cursor,
    float2*       __restrict__ perm)
{
    int i = blockIdx.x * 256 + threadIdx.x;
    if (i >= N_EDGE / 4) return;
    int4   ni = node_in4[i];
    int4   no = node_out4[i];
    int4   rl = relation4[i];
    float4 w  = ew4[i];

    unsigned p0 = atomicAdd(&cursor[no.x], 1u);
    unsigned p1 = atomicAdd(&cursor[no.y], 1u);
    unsigned p2 = atomicAdd(&cursor[no.z], 1u);
    unsigned p3 = atomicAdd(&cursor[no.w], 1u);

    perm[p0] = make_float2(w.x, __uint_as_float(
        (unsigned)ni.x | ((unsigned)rl.x << 16) | (((unsigned)no.x & 31u) << 19)));
    perm[p1] = make_float2(w.y, __uint_as_float(
        (unsigned)ni.y | ((unsigned)rl.y << 16) | (((unsigned)no.y & 31u) << 19)));
    perm[p2] = make_float2(w.z, __uint_as_float(
        (unsigned)ni.z | ((unsigned)rl.z << 16) | (((unsigned)no.z & 31u) << 19)));
    perm[p3] = make_float2(w.w, __uint_as_float(
        (unsigned)ni.w | ((unsigned)rl.w << 16) | (((unsigned)no.w & 31u) << 19)));
}

// ===========================================================================
// K4: fused segmented-sum + matmul + epilogue
//   256 threads = 4 waves. Phase 1: HALF-WAVE per node — lanes 0-31 walk node
//   2q, lanes 32-63 walk node 2q+1 (wave w owns nodes w*8..w*8+7). Each lane
//   holds a float4 accumulator (32 lanes x 16 B = full 128-dim row); one load
//   instruction covers 2 edges; unroll-4 keeps 8 edges in flight per wave.
//   No atomics on the accumulation path (exclusive node ownership).
// ===========================================================================
__global__ __launch_bounds__(256) void rgc_fused(
    const float*    __restrict__ x,        // [N_NODE, DIM]
    const float*    __restrict__ W,        // [DIM, DIM] (k, j)
    const float*    __restrict__ b,        // [DIM]
    const float*    __restrict__ rel_emb,  // [NUM_REL, DIM]
    const unsigned* __restrict__ offsets,  // [N_NODE+1]
    const float2*   __restrict__ perm,     // [N_EDGE]
    float*          __restrict__ out)      // [N_NODE, DIM]
{
    __shared__ float    rel_lds[NUM_REL * DIM];   // 4 KB
    __shared__ float    aggs[NPC][DIM];           // 16 KB
    __shared__ float    cnts[NPC][NUM_REL];       // 1 KB
    __shared__ unsigned bnd[NPC + 1];

    const int tid  = threadIdx.x;
    const int slot = tid >> 6;           // wave 0..3
    const int lane = tid & 63;
    const int h    = lane >> 5;          // half 0/1
    const int l32  = lane & 31;          // lane within half
    const unsigned jo = (unsigned)(l32 * 16);   // float4 byte offset in a row

    for (int i = tid; i < NUM_REL * DIM; i += 256) rel_lds[i] = rel_emb[i];
    cnts[tid >> 3][tid & 7] = 0.f;
    const int base = blockIdx.x * NPC;
    if (tid <= NPC) {
        int idx = base + tid; if (idx > N_NODE) idx = N_NODE;
        bnd[tid] = offsets[idx];
    }
    __syncthreads();

    const char* xb = (const char*)x;

    // ---- phase 1: half-wave register-accumulating segment walk ----
    for (int q = 0; q < NPC / 8; ++q) {
        const int l = slot * 8 + q * 2 + h;   // local node this half owns
        const int s = (int)bnd[l];
        const int e = (int)bnd[l + 1];
        float4 acc = make_float4(0.f, 0.f, 0.f, 0.f);
        int i = s;
        #define EDGE(ii)                                                       \
        {                                                                      \
            float2 p = perm[ii];                                               \
            unsigned kk = __float_as_uint(p.y);                                \
            const float4 v = *(const float4*)(xb + (((kk & 0xFFFFu) << 9) + jo)); \
            acc.x += p.x * v.x; acc.y += p.x * v.y;                            \
            acc.z += p.x * v.z; acc.w += p.x * v.w;                            \
            if (l32 == 0) atomicAdd(&cnts[l][(kk >> 16) & 7u], p.x);           \
        }
        for (; i + 4 <= e; i += 4) { EDGE(i) EDGE(i + 1) EDGE(i + 2) EDGE(i + 3) }
        for (; i < e; ++i) EDGE(i)
        #undef EDGE
        *(float4*)&aggs[l][l32 * 4] = acc;
    }
    __syncthreads();

    // ---- phase 2: [8 nodes x 128] @ [128 x 128] per wave ----
    const int g = slot;
    float2 mm[8];
    #pragma unroll
    for (int m = 0; m < 8; ++m) mm[m] = make_float2(0.f, 0.f);

    for (int k = 0; k < DIM; k += 4) {
        const float2 wv0 = *(const float2*)&W[(k + 0) * DIM + lane * 2];
        const float2 wv1 = *(const float2*)&W[(k + 1) * DIM + lane * 2];
        const float2 wv2 = *(const float2*)&W[(k + 2) * DIM + lane * 2];
        const float2 wv3 = *(const float2*)&W[(k + 3) * DIM + lane * 2];
        #pragma unroll
        for (int m = 0; m < 8; ++m) {
            const float4 av = *(const float4*)&aggs[g * 8 + m][k];
            mm[m].x += av.x * wv0.x + av.y * wv1.x + av.z * wv2.x + av.w * wv3.x;
            mm[m].y += av.x * wv0.y + av.y * wv1.y + av.z * wv2.y + av.w * wv3.y;
        }
    }

    // ---- epilogue ----
    const float2 bv = *(const float2*)&b[lane * 2];
    float2 rv[NUM_REL];
    #pragma unroll
    for (int r = 0; r < NUM_REL; ++r)
        rv[r] = *(const float2*)&rel_lds[r * DIM + lane * 2];

    #pragma unroll
    for (int m = 0; m < 8; ++m) {
        const int l = g * 8 + m;
        const int n = base + l;
        if (n < N_NODE) {
            float dg = 0.f, rbx = 0.f, rby = 0.f;
            #pragma unroll
            for (int r = 0; r < NUM_REL; ++r) {
                const float c = cnts[l][r];
                dg  += c;
                rbx += c * rv[r].x;
                rby += c * rv[r].y;
            }
            const float inv = 1.0f / (dg + EPS);
            float yx = (mm[m].x + dg * bv.x + rbx) * inv;
            float yy = (mm[m].y + dg * bv.y + rby) * inv;
            *(float2*)&out[(size_t)n * DIM + lane * 2] =
                make_float2(fmaxf(yx, 0.f), fmaxf(yy, 0.f));
        }
    }
}

// ===========================================================================
// Fallback path (old atomic scatter) in case ws_size is too small
// ===========================================================================
__global__ __launch_bounds__(256) void rgc_scatter(
    const float* __restrict__ x,
    const int*   __restrict__ node_in,
    const int*   __restrict__ node_out,
    const int*   __restrict__ relation,
    const float* __restrict__ ew,
    float*       __restrict__ agg,
    float*       __restrict__ cnt)
{
    int gid  = blockIdx.x * 256 + threadIdx.x;
    int e    = gid >> 5;
    int lane = gid & 31;
    if (e >= N_EDGE) return;
    int   src = node_in[e];
    int   dst = node_out[e];
    float w   = ew[e];
    const float4* x4 = reinterpret_cast<const float4*>(x + (size_t)src * DIM);
    float4 v = x4[lane];
    float* o = agg + (size_t)dst * DIM + lane * 4;
    atomicAdd(o + 0, v.x * w);
    atomicAdd(o + 1, v.y * w);
    atomicAdd(o + 2, v.z * w);
    atomicAdd(o + 3, v.w * w);
    if (lane == 0) atomicAdd(&cnt[(size_t)dst * NUM_REL + relation[e]], w);
}

__global__ __launch_bounds__(256) void rgc_finalize(
    const float* __restrict__ W,
    const float* __restrict__ b,
    const float* __restrict__ rel_emb,
    const float* __restrict__ cnt,
    float*       __restrict__ out,
    int nodes_per_block)
{
    __shared__ float Ws[DIM * DIM];
    __shared__ float bs[DIM];
    __shared__ float rs[NUM_REL * DIM];
    __shared__ float aggs2[2][DIM];
    for (int i = threadIdx.x; i < DIM * DIM; i += 256) Ws[i] = W[i];
    for (int i = threadIdx.x; i < DIM; i += 256)       bs[i] = b[i];
    for (int i = threadIdx.x; i < NUM_REL * DIM; i += 256) rs[i] = rel_emb[i];
    const int half = threadIdx.x >> 7;
    const int j    = threadIdx.x & 127;
    const int base = blockIdx.x * nodes_per_block;
    for (int nn = 0; nn < nodes_per_block; nn += 2) {
        const int n = base + nn + half;
        __syncthreads();
        if (n < N_NODE) aggs2[half][j] = out[(size_t)n * DIM + j];
        __syncthreads();
        if (n < N_NODE) {
            float acc = 0.f;
            #pragma unroll 16
            for (int k = 0; k < DIM; ++k)
                acc += aggs2[half][k] * Ws[k * DIM + j];
            float deg = 0.f, rbv = 0.f;
            #pragma unroll
            for (int r = 0; r < NUM_REL; ++r) {
                float c = cnt[(size_t)n * NUM_REL + r];
                deg += c;
                rbv += c * rs[r * DIM + j];
            }
            float y = (acc + deg * bs[j] + rbv) / (deg + EPS);
            out[(size_t)n * DIM + j] = fmaxf(y, 0.f);
        }
    }
}

// ===========================================================================
extern "C" void kernel_launch(void* const* d_in, const int* in_sizes, int n_in,
                              void* d_out, int out_size, void* d_ws, size_t ws_size,
                              hipStream_t stream) {
    const float* x        = (const float*)d_in[0];
    const int*   node_in  = (const int*)  d_in[1];
    const int*   node_out = (const int*)  d_in[2];
    const int*   relation = (const int*)  d_in[3];
    const float* ew       = (const float*)d_in[4];
    const float* W        = (const float*)d_in[5];
    const float* b        = (const float*)d_in[6];
    const float* rel_emb  = (const float*)d_in[7];
    float* out = (float*)d_out;

    // ws layout
    const size_t OFF_HIST   = 0;                       // u32[N_NODE]      200000 B
    const size_t OFF_CURSOR = 200000;                  // u32[N_NODE]      200000 B
    const size_t OFF_OFFS   = 400000;                  // u32[N_NODE+1]    200004 B
    const size_t OFF_PART   = 600064;                  // u32[SCAN_TILES]  784 B
    const size_t OFF_PERM   = 601088;                  // float2[N_EDGE]   5 MB
    const size_t WS_NEEDED  = OFF_PERM + (size_t)N_EDGE * sizeof(float2);

    if (ws_size < WS_NEEDED) {
        // fallback: atomic path (needs 1.6 MB)
        float* cnt = (float*)d_ws;
        hipMemsetAsync(d_out, 0, (size_t)N_NODE * DIM * sizeof(float), stream);
        hipMemsetAsync(cnt,   0, (size_t)N_NODE * NUM_REL * sizeof(float), stream);
        dim3 g1((N_EDGE * 32 + 255) / 256);
        rgc_scatter<<<g1, 256, 0, stream>>>(x, node_in, node_out, relation, ew, out, cnt);
        const int NPB = 16;
        dim3 g2((N_NODE + NPB - 1) / NPB);
        rgc_finalize<<<g2, 256, 0, stream>>>(W, b, rel_emb, cnt, out, NPB);
        return;
    }

    unsigned* hist    = (unsigned*)((char*)d_ws + OFF_HIST);
    unsigned* cursor  = (unsigned*)((char*)d_ws + OFF_CURSOR);
    unsigned* offsets = (unsigned*)((char*)d_ws + OFF_OFFS);
    unsigned* partial = (unsigned*)((char*)d_ws + OFF_PART);
    float2*   perm    = (float2*)  ((char*)d_ws + OFF_PERM);

    hipMemsetAsync(hist, 0, (size_t)N_NODE * sizeof(unsigned), stream);

    dim3 g4((N_EDGE / 4 + 255) / 256);   // 611
    rgc_hist<<<g4, 256, 0, stream>>>((const int4*)node_out, hist);
    rgc_scan1<<<SCAN_TILES, 256, 0, stream>>>(hist, partial);
    rgc_scan3<<<SCAN_TILES, 256, 0, stream>>>(hist, partial, offsets, cursor);
    rgc_permute<<<g4, 256, 0, stream>>>((const int4*)node_in, (const int4*)node_out,
                                        (const int4*)relation, (const float4*)ew,
                                        cursor, perm);

    dim3 gf((N_NODE + NPC - 1) / NPC);   // 1563
    rgc_fused<<<gf, 256, 0, stream>>>(x, W, b, rel_emb, offsets, perm, out);
}